// Round 5
// baseline (167.064 us; speedup 1.0000x reference)
//
#include <hip/hip_runtime.h>

#define HID 50
#define TSTEPS 512

typedef float f32x2 __attribute__((ext_vector_type(2)));
typedef float f32x4 __attribute__((ext_vector_type(4)));

// Packed fp32 (VOP3P, full-rate on CDNA): 2 FMAs per instruction.
// Proven to assemble on gfx950 (round 3 run).
__device__ __forceinline__ void pk_fma(f32x2& d, f32x2 a, f32x2 b) {
    asm("v_pk_fma_f32 %0, %1, %2, %0" : "+v"(d) : "v"(a), "v"(b));
}
__device__ __forceinline__ f32x2 pk_mul(f32x2 a, f32x2 b) {
    f32x2 d;
    asm("v_pk_mul_f32 %0, %1, %2" : "=v"(d) : "v"(a), "v"(b));
    return d;
}
__device__ __forceinline__ void pk_add(f32x2& d, f32x2 a) {
    asm("v_pk_add_f32 %0, %1, %0" : "+v"(d) : "v"(a));
}

// Single-wave workgroup: LDS ops from one wave complete in order, so
// write->read visibility needs only a write-ack wait, NOT s_barrier and NOT
// the compiler's pre-barrier vmcnt(0) drain (which was stalling the x
// prefetch into the recurrence chain).
__device__ __forceinline__ void lds_fence() {
    asm volatile("s_waitcnt lgkmcnt(0)" ::: "memory");
}

// One wave per batch element. Lane j owns h[j]; row j of W_hh (pre-scaled by
// 2*log2e, zero-padded to 52) in 26 f32x2 pairs. h broadcast via LDS:
// 13x ds_read_b128 same-address broadcast (conflict-free). 26 pk_fma/step.
// Grid is fixed at 2048 waves = 2/SIMD: waves_per_eu(2,2) -> 256-VGPR budget.
__global__ __launch_bounds__(64) __attribute__((amdgpu_waves_per_eu(2, 2)))
void rnn_fused(
    const float* __restrict__ x,      // [B, 512, 1]
    const float* __restrict__ W_ih,   // [50, 1]
    const float* __restrict__ W_hh,   // [50, 50]
    const float* __restrict__ b_ih,   // [50]
    const float* __restrict__ b_hh,   // [50]
    const float* __restrict__ W_fc,   // [1, 50]
    const float* __restrict__ b_fc,   // [1]
    float* __restrict__ out)          // [B, 1]
{
    const int b = blockIdx.x;
    const int j = threadIdx.x;        // 0..63; lanes 50..63 duplicate row 0
    __shared__ __align__(16) float hlds[64];
    __shared__ __align__(16) float xbuf[64];

    const int jj = (j < HID) ? j : 0;
    const float SC = 2.8853900817779268f;   // 2*log2(e)

    // Pair m covers h[2m],h[2m+1]; pair 25 (k=50,51) is zero so the 13th 16B
    // read (hlds[48..51], holding duplicated h[0] in slots 50/51) is inert.
    f32x2 w2[26];
#pragma unroll
    for (int m = 0; m < 25; ++m) {
        f32x2 t;
        t.x = W_hh[jj * HID + 2 * m]     * SC;
        t.y = W_hh[jj * HID + 2 * m + 1] * SC;
        w2[m] = t;
    }
    w2[25] = (f32x2)(0.0f);

    const float wih  = W_ih[jj] * SC;
    const float btot = (b_ih[jj] + b_hh[jj]) * SC;
    const float wfc  = (j < HID) ? W_fc[jj] : 0.0f;
    const float bfc  = b_fc[0];

    const float* xb = x + (size_t)b * TSTEPS;
    float xv = xb[j];                 // 64 timesteps of x, one per lane
    float hn = 0.0f;

    for (int c = 0; c < TSTEPS / 64; ++c) {
        xbuf[j] = xv;                 // stage chunk's x (in-order DS, fenced below)
        float xv_next = 0.0f;
        if (c + 1 < TSTEPS / 64) xv_next = xb[(c + 1) * 64 + j];

        for (int g = 0; g < 8; ++g) {
#pragma unroll
            for (int ii = 0; ii < 8; ++ii) {
                const int t = g * 8 + ii;

                hlds[j] = hn;                           // publish h (step t)
                const float xt  = xbuf[t];              // uniform addr broadcast
                lds_fence();                            // write-ack; reads below
                                                        // are HW-ordered after it
                const float xtc = fmaf(xt, wih, btot);

                const f32x4* h4 = (const f32x4*)hlds;
                f32x2 a0 = (f32x2)(0.0f), a1 = (f32x2)(0.0f);
                f32x2 a2 = (f32x2)(0.0f), a3 = (f32x2)(0.0f);
#pragma unroll
                for (int q = 0; q < 13; ++q) {
                    const f32x4 p = h4[q];              // ds_read_b128 broadcast
                    const f32x2 plo = __builtin_shufflevector(p, p, 0, 1);
                    const f32x2 phi = __builtin_shufflevector(p, p, 2, 3);
                    if ((q & 1) == 0) {
                        pk_fma(a0, plo, w2[2 * q]);
                        pk_fma(a1, phi, w2[2 * q + 1]);
                    } else {
                        pk_fma(a2, plo, w2[2 * q]);
                        pk_fma(a3, phi, w2[2 * q + 1]);
                    }
                }
                pk_add(a0, a1);
                pk_add(a2, a3);
                pk_add(a0, a2);
                const float z = (a0.x + a0.y) + xtc;    // scaled by 2*log2e

                // tanh(s) = 1 - 2/(exp2(z)+1); saturates correctly at +-inf
                const float e = __builtin_amdgcn_exp2f(z);
                const float r = __builtin_amdgcn_rcpf(e + 1.0f);
                hn = fmaf(-2.0f, r, 1.0f);
            }
        }
        xv = xv_next;
    }

    // out[b] = sum_j h[j] * W_fc[j] + b_fc  (lanes >= 50 contribute 0)
    float pr = hn * wfc;
#pragma unroll
    for (int off = 32; off >= 1; off >>= 1) pr += __shfl_xor(pr, off);
    if (j == 0) out[b] = pr + bfc;
}

extern "C" void kernel_launch(void* const* d_in, const int* in_sizes, int n_in,
                              void* d_out, int out_size, void* d_ws, size_t ws_size,
                              hipStream_t stream) {
    (void)d_ws; (void)ws_size; (void)n_in; (void)out_size;
    const float* x    = (const float*)d_in[0];
    const float* W_ih = (const float*)d_in[1];
    const float* W_hh = (const float*)d_in[2];
    const float* b_ih = (const float*)d_in[3];
    const float* b_hh = (const float*)d_in[4];
    const float* W_fc = (const float*)d_in[5];
    const float* b_fc = (const float*)d_in[6];
    float* out = (float*)d_out;

    const int B = in_sizes[0] / TSTEPS;   // 2048
    rnn_fused<<<dim3(B), dim3(64), 0, stream>>>(x, W_ih, W_hh, b_ih, b_hh, W_fc, b_fc, out);
}

// Round 7
// 152.224 us; speedup vs baseline: 1.0975x; 1.0975x over previous
//
#include <hip/hip_runtime.h>

#define HID 50
#define TSTEPS 512

typedef float f32x4 __attribute__((ext_vector_type(4)));

// One wave (64 lanes) per batch element; lane j owns h[j], row j of W_hh in
// 50 VGPRs (pre-scaled by 2*log2e so tanh needs no input multiply).
//
// Wave-synchronous LDS broadcast (the point of this round): DS ops from a
// single wave are processed IN ORDER by the LDS pipeline, so for a
// single-wave workgroup the cross-lane RAW  (lane j writes hlds[j]; all
// lanes then read hlds[0..51])  needs NO barrier and NO explicit waitcnt
// between write and reads. The write's runtime index j may-aliases every
// constant-offset read quad, so the compiler preserves program order; it
// only inserts lgkmcnt for the read results' register availability. This
// removes the LDS write-ack (~100cy) and barrier drain from the serial
// recurrence chain. Scalar FMAs only: v_pk_fma_f32 measured half-rate on
// gfx950 (round 5) -- no packed math.
__global__ __launch_bounds__(64) __attribute__((amdgpu_waves_per_eu(2, 2)))
void rnn_fused(
    const float* __restrict__ x,      // [B, 512, 1]
    const float* __restrict__ W_ih,   // [50, 1]
    const float* __restrict__ W_hh,   // [50, 50]
    const float* __restrict__ b_ih,   // [50]
    const float* __restrict__ b_hh,   // [50]
    const float* __restrict__ W_fc,   // [1, 50]
    const float* __restrict__ b_fc,   // [1]
    float* __restrict__ out)          // [B, 1]
{
    const int b = blockIdx.x;
    const int j = threadIdx.x;        // 0..63; lanes 50..63 duplicate row 0
    __shared__ __align__(16) float hlds[64];
    __shared__ __align__(16) float xbuf[64];

    const int jj = (j < HID) ? j : 0;
    const float SC = 2.8853900817779268f;   // 2*log2(e)

    // w[50..51] = 0 so the 13th 16B read (hlds[48..51], slots 50/51 hold
    // lanes 50/51's duplicated h[0]) contributes nothing.
    float w[52];
#pragma unroll
    for (int k = 0; k < HID; ++k) w[k] = W_hh[jj * HID + k] * SC;
    w[50] = 0.0f;
    w[51] = 0.0f;

    const float wih  = W_ih[jj] * SC;
    const float btot = (b_ih[jj] + b_hh[jj]) * SC;
    const float wfc  = (j < HID) ? W_fc[jj] : 0.0f;
    const float bfc  = b_fc[0];

    const float* xb = x + (size_t)b * TSTEPS;
    float xv = xb[j];                 // 64 timesteps of x, one per lane
    float hn = 0.0f;

    for (int c = 0; c < TSTEPS / 64; ++c) {
        xbuf[j] = xv;                 // stage chunk's x (same-wave in-order DS)
        float xv_next = 0.0f;
        if (c + 1 < TSTEPS / 64) xv_next = xb[(c + 1) * 64 + j];

        for (int g = 0; g < 8; ++g) {
#pragma unroll
            for (int ii = 0; ii < 8; ++ii) {
                const int t = g * 8 + ii;

                hlds[j] = hn;                     // publish h(t) -- no fence:
                                                  // reads below are HW-ordered
                const float xt = xbuf[t];         // uniform addr -> broadcast
                const float xtc = fmaf(xt, wih, btot);

                const f32x4* h4 = (const f32x4*)hlds;
                float a0 = xtc, a1 = 0.0f, a2 = 0.0f, a3 = 0.0f;
#pragma unroll
                for (int q = 0; q < 13; ++q) {
                    const f32x4 p = h4[q];        // ds_read_b128 broadcast
                    a0 = fmaf(p.x, w[4 * q + 0], a0);
                    a1 = fmaf(p.y, w[4 * q + 1], a1);
                    a2 = fmaf(p.z, w[4 * q + 2], a2);
                    a3 = fmaf(p.w, w[4 * q + 3], a3);
                }
                const float z = (a0 + a1) + (a2 + a3);   // scaled by 2*log2e

                // tanh(s) = 1 - 2/(exp2(z)+1); saturates correctly at +-inf
                const float e = __builtin_amdgcn_exp2f(z);
                const float r = __builtin_amdgcn_rcpf(e + 1.0f);
                hn = fmaf(-2.0f, r, 1.0f);
            }
        }
        xv = xv_next;
    }

    // out[b] = sum_j h[j] * W_fc[j] + b_fc  (lanes >= 50 contribute 0)
    float pr = hn * wfc;
#pragma unroll
    for (int off = 32; off >= 1; off >>= 1) pr += __shfl_xor(pr, off);
    if (j == 0) out[b] = pr + bfc;
}

extern "C" void kernel_launch(void* const* d_in, const int* in_sizes, int n_in,
                              void* d_out, int out_size, void* d_ws, size_t ws_size,
                              hipStream_t stream) {
    (void)d_ws; (void)ws_size; (void)n_in; (void)out_size;
    const float* x    = (const float*)d_in[0];
    const float* W_ih = (const float*)d_in[1];
    const float* W_hh = (const float*)d_in[2];
    const float* b_ih = (const float*)d_in[3];
    const float* b_hh = (const float*)d_in[4];
    const float* W_fc = (const float*)d_in[5];
    const float* b_fc = (const float*)d_in[6];
    float* out = (float*)d_out;

    const int B = in_sizes[0] / TSTEPS;   // 2048
    rnn_fused<<<dim3(B), dim3(64), 0, stream>>>(x, W_ih, W_hh, b_ih, b_hh, W_fc, b_fc, out);
}